// Round 2
// baseline (510.124 us; speedup 1.0000x reference)
//
#include <hip/hip_runtime.h>
#include <hip/hip_bf16.h>
#include <math.h>

// Problem: B=8, NQ=1024, NKV=2048, D=1024, H=16, HD=64, inner=1024.
// Inputs/outputs are f32 storage (per reference dtypes); internal compute is
// bf16 MFMA with fp32 accumulation (harness threshold is bf16-scale, 2% of max).
//
// ws layout (ushort elems):
//   wqT 1M | wkT 1M | wvT 1M | woT 1M | latB 8M | datB 16M | Q 8M | K 16M
//   | Vt 16M | AO 8M   = 76M elems = 152 MB

using short8 = __attribute__((ext_vector_type(8))) short;
using f32x4  = __attribute__((ext_vector_type(4))) float;

__device__ __forceinline__ float bf2f(ushort b) {
    unsigned u = ((unsigned)b) << 16;
    return __builtin_bit_cast(float, u);
}
__device__ __forceinline__ ushort f2bf(float f) {
    unsigned u = __builtin_bit_cast(unsigned, f);
    u = (u + 0x7FFFu + ((u >> 16) & 1u)) >> 16;
    return (ushort)u;
}

// async global->LDS, 16B per lane. LDS dest = wave-uniform base + lane*16.
__device__ __forceinline__ void gld_lds16(const ushort* g, ushort* l) {
    __builtin_amdgcn_global_load_lds(
        (const __attribute__((address_space(1))) unsigned int*)(const void*)g,
        (__attribute__((address_space(3))) unsigned int*)(void*)l,
        16, 0, 0);
}

// ---------------------------------------------------------------------------
// f32 -> bf16 conversion, 8 elems/thread (n must be multiple of 8)
// ---------------------------------------------------------------------------
__global__ void cvt_bf16(const float* __restrict__ in, ushort* __restrict__ out, int n) {
    int i = (blockIdx.x * blockDim.x + threadIdx.x) * 8;
    if (i >= n) return;
    float4 a = *(const float4*)(in + i);
    float4 b = *(const float4*)(in + i + 4);
    short8 o;
    o[0] = (short)f2bf(a.x); o[1] = (short)f2bf(a.y);
    o[2] = (short)f2bf(a.z); o[3] = (short)f2bf(a.w);
    o[4] = (short)f2bf(b.x); o[5] = (short)f2bf(b.y);
    o[6] = (short)f2bf(b.z); o[7] = (short)f2bf(b.w);
    *(short8*)(out + i) = o;
}

// ---------------------------------------------------------------------------
// Transpose + convert the 4 weight matrices (each 1024x1024 f32):
// out_bf16[n][k] = in_f32[k][n]
// ---------------------------------------------------------------------------
__global__ void transpose_w(const float* __restrict__ w0, const float* __restrict__ w1,
                            const float* __restrict__ w2, const float* __restrict__ w3,
                            ushort* __restrict__ o0, ushort* __restrict__ o1,
                            ushort* __restrict__ o2, ushort* __restrict__ o3) {
    __shared__ ushort tile[32][33];
    int z = blockIdx.z;
    const float* in = (z == 0) ? w0 : (z == 1) ? w1 : (z == 2) ? w2 : w3;
    ushort* out     = (z == 0) ? o0 : (z == 1) ? o1 : (z == 2) ? o2 : o3;
    int tx = threadIdx.x, ty = threadIdx.y;
    int x = blockIdx.x * 32 + tx;
    int y = blockIdx.y * 32;
#pragma unroll
    for (int i = 0; i < 32; i += 8)
        tile[ty + i][tx] = f2bf(in[(size_t)(y + ty + i) * 1024 + x]);
    __syncthreads();
    int x2 = blockIdx.y * 32 + tx;
    int y2 = blockIdx.x * 32;
#pragma unroll
    for (int i = 0; i < 32; i += 8)
        out[(size_t)(y2 + ty + i) * 1024 + x2] = tile[tx][ty + i];
}

// ---------------------------------------------------------------------------
// GEMM: C[m][n] = sum_k A[m][k] * Bt[n][k] + bias[n]      (N = K = 1024 fixed)
// A, Bt bf16; bias f32. 128x128 tile, BK=32, 4 waves, mfma 16x16x32 bf16.
// MODE 0: C bf16 row-major [M][1024]
// MODE 1: (V projection) C bf16 transposed per-head:
//         m = b*2048+kv, n = h*64+d  ->  C[(b*1024 + n)*2048 + kv]
// MODE 2: C f32 row-major [M][1024]
// ---------------------------------------------------------------------------
template <int MODE>
__global__ void gemm_bt(const ushort* __restrict__ A, const ushort* __restrict__ Bt,
                        const float* __restrict__ bias, void* __restrict__ Cv,
                        int K) {
    __shared__ __align__(16) ushort As[128 * 32];
    __shared__ __align__(16) ushort Bs[128 * 32];
    const int tid  = threadIdx.x;
    const int wave = tid >> 6, lane = tid & 63;
    const int l15 = lane & 15, quad = lane >> 4;
    const int wm = wave & 1, wn = wave >> 1;
    const int m0 = blockIdx.y * 128;
    const int n0 = blockIdx.x * 128;

    f32x4 acc[4][4] = {};

    for (int k0 = 0; k0 < K; k0 += 32) {
        __syncthreads();  // previous iteration's LDS reads complete
#pragma unroll
        for (int i = 0; i < 2; ++i) {
            int f   = (i * 256 + tid) * 8;   // flat elem idx in 128x32 tile
            int row = f >> 5, col = f & 31;
            gld_lds16(A  + (size_t)(m0 + row) * K + k0 + col, As + (i * 256 + wave * 64) * 8);
            gld_lds16(Bt + (size_t)(n0 + row) * K + k0 + col, Bs + (i * 256 + wave * 64) * 8);
        }
        __syncthreads();  // drains vmcnt -> staged data visible

        short8 a[4], b[4];
#pragma unroll
        for (int mi = 0; mi < 4; ++mi)
            a[mi] = *(const short8*)(As + (wm * 64 + mi * 16 + l15) * 32 + quad * 8);
#pragma unroll
        for (int ni = 0; ni < 4; ++ni)
            b[ni] = *(const short8*)(Bs + (wn * 64 + ni * 16 + l15) * 32 + quad * 8);
#pragma unroll
        for (int mi = 0; mi < 4; ++mi)
#pragma unroll
            for (int ni = 0; ni < 4; ++ni)
                acc[mi][ni] = __builtin_amdgcn_mfma_f32_16x16x32_bf16(a[mi], b[ni], acc[mi][ni], 0, 0, 0);
    }

    // epilogue: C/D layout col=lane&15, row=quad*4+reg
    float bv[4];
    int   cols[4];
#pragma unroll
    for (int ni = 0; ni < 4; ++ni) {
        cols[ni] = n0 + wn * 64 + ni * 16 + l15;
        bv[ni]   = bias[cols[ni]];
    }
#pragma unroll
    for (int mi = 0; mi < 4; ++mi) {
        int rbase = m0 + wm * 64 + mi * 16 + quad * 4;
#pragma unroll
        for (int ni = 0; ni < 4; ++ni) {
#pragma unroll
            for (int rr = 0; rr < 4; ++rr) {
                int   row = rbase + rr;
                float v   = acc[mi][ni][rr] + bv[ni];
                if (MODE == 0)
                    ((ushort*)Cv)[(size_t)row * 1024 + cols[ni]] = f2bf(v);
                else if (MODE == 1)
                    ((ushort*)Cv)[((size_t)((row >> 11) * 1024 + cols[ni])) * 2048 + (row & 2047)] = f2bf(v);
                else
                    ((float*)Cv)[(size_t)row * 1024 + cols[ni]] = v;
            }
        }
    }
}

// ---------------------------------------------------------------------------
// Fused flash-style attention (all bf16 in/out, fp32 accumulate).
// Grid: 1024 blocks = (b, h, q-tile of 128). 256 threads = 4 waves, each wave
// owns 32 q rows. KV tiles of 128, online softmax, P->LDS->A-layout round trip.
// Q: [b][nq][h*64+d]; K: [b][nkv][h*64+d]; Vt: [b*1024 + h*64 + d][kv].
// O (AO): [b][nq][h*64+d].
// ---------------------------------------------------------------------------
__global__ __launch_bounds__(256, 2) void attn_fused(const ushort* __restrict__ Q,
                                                     const ushort* __restrict__ K,
                                                     const ushort* __restrict__ Vt,
                                                     ushort* __restrict__ O) {
    // Qs [128][72], KsPs union: Ks [128][72] / Ps [128][136], Vts [64][136]
    __shared__ __align__(16) ushort smem[9216 + 17408 + 8704];
    ushort* Qs   = smem;
    ushort* KsPs = smem + 9216;
    ushort* Vts  = smem + 9216 + 17408;

    const int tid  = threadIdx.x;
    const int wave = tid >> 6, lane = tid & 63;
    const int l15 = lane & 15, quad = lane >> 4;
    const int bx = blockIdx.x;
    const int qt = bx & 7, h = (bx >> 3) & 15, b = bx >> 7;
    const int q0 = qt * 128;

    const ushort* Qg = Q + ((size_t)(b * 1024 + q0)) * 1024 + h * 64;
    const ushort* Kg = K + ((size_t)(b * 2048)) * 1024 + h * 64;
    const ushort* Vg = Vt + ((size_t)(b * 1024 + h * 64)) * 2048;

    // stage Q tile [128][64] -> Qs[128][72]
#pragma unroll
    for (int i = 0; i < 4; ++i) {
        int e = i * 256 + tid;               // 8-elem groups
        int row = e >> 3, col = (e & 7) * 8;
        *(short8*)(Qs + row * 72 + col) = *(const short8*)(Qg + (size_t)row * 1024 + col);
    }

    f32x4 Oacc[2][4] = {};
    float m_run[2][4], l_run[2][4];
#pragma unroll
    for (int mi = 0; mi < 2; ++mi)
#pragma unroll
        for (int rr = 0; rr < 4; ++rr) { m_run[mi][rr] = -INFINITY; l_run[mi][rr] = 0.f; }

    for (int kv0 = 0; kv0 < 2048; kv0 += 128) {
        // stage K tile [128][64] -> KsPs[128][72]; V tile -> Vts[64][136]
#pragma unroll
        for (int i = 0; i < 4; ++i) {
            int e = i * 256 + tid;
            int row = e >> 3, col = (e & 7) * 8;
            *(short8*)(KsPs + row * 72 + col) =
                *(const short8*)(Kg + (size_t)(kv0 + row) * 1024 + col);
            int d = e >> 4, kvc = (e & 15) * 8;
            *(short8*)(Vts + d * 136 + kvc) =
                *(const short8*)(Vg + (size_t)d * 2048 + kv0 + kvc);
        }
        __syncthreads();

        // S = Q K^T  (wave rows: wave*32 .. +31; cols 0..127)
        f32x4 s[2][8] = {};
#pragma unroll
        for (int ks = 0; ks < 2; ++ks) {
            short8 a[2];
#pragma unroll
            for (int mi = 0; mi < 2; ++mi)
                a[mi] = *(const short8*)(Qs + (wave * 32 + mi * 16 + l15) * 72 + ks * 32 + quad * 8);
#pragma unroll
            for (int nf = 0; nf < 8; ++nf) {
                short8 bb = *(const short8*)(KsPs + (nf * 16 + l15) * 72 + ks * 32 + quad * 8);
#pragma unroll
                for (int mi = 0; mi < 2; ++mi)
                    s[mi][nf] = __builtin_amdgcn_mfma_f32_16x16x32_bf16(a[mi], bb, s[mi][nf], 0, 0, 0);
            }
        }

        // scale + online softmax (rows = quad*4+rr, cols spread over 16 lanes of quad)
#pragma unroll
        for (int mi = 0; mi < 2; ++mi) {
#pragma unroll
            for (int rr = 0; rr < 4; ++rr) {
                float mx = -INFINITY;
#pragma unroll
                for (int nf = 0; nf < 8; ++nf) {
                    s[mi][nf][rr] *= 0.125f;  // HD^-0.5
                    mx = fmaxf(mx, s[mi][nf][rr]);
                }
                mx = fmaxf(mx, __shfl_xor(mx, 1));
                mx = fmaxf(mx, __shfl_xor(mx, 2));
                mx = fmaxf(mx, __shfl_xor(mx, 4));
                mx = fmaxf(mx, __shfl_xor(mx, 8));
                float mold  = m_run[mi][rr];
                float mnew  = fmaxf(mold, mx);
                float alpha = __expf(mold - mnew);
                float rsum  = 0.f;
#pragma unroll
                for (int nf = 0; nf < 8; ++nf) {
                    float p = __expf(s[mi][nf][rr] - mnew);
                    s[mi][nf][rr] = p;
                    rsum += p;
                }
                rsum += __shfl_xor(rsum, 1);
                rsum += __shfl_xor(rsum, 2);
                rsum += __shfl_xor(rsum, 4);
                rsum += __shfl_xor(rsum, 8);
                m_run[mi][rr] = mnew;
                l_run[mi][rr] = l_run[mi][rr] * alpha + rsum;
#pragma unroll
                for (int nd = 0; nd < 4; ++nd) Oacc[mi][nd][rr] *= alpha;
            }
        }

        __syncthreads();  // all waves finished reading Ks before P overwrites it

        // write P (C-layout) -> Ps bf16 [128][136], per-wave rows
#pragma unroll
        for (int mi = 0; mi < 2; ++mi)
#pragma unroll
            for (int nf = 0; nf < 8; ++nf)
#pragma unroll
                for (int rr = 0; rr < 4; ++rr)
                    KsPs[(wave * 32 + mi * 16 + quad * 4 + rr) * 136 + nf * 16 + l15] =
                        f2bf(s[mi][nf][rr]);

        // O += P V   (wave-local Ps RAW handled by compiler lgkmcnt)
#pragma unroll
        for (int ks2 = 0; ks2 < 4; ++ks2) {
            short8 a[2];
#pragma unroll
            for (int mi = 0; mi < 2; ++mi)
                a[mi] = *(const short8*)(KsPs + (wave * 32 + mi * 16 + l15) * 136 + ks2 * 32 + quad * 8);
#pragma unroll
            for (int nd = 0; nd < 4; ++nd) {
                short8 bb = *(const short8*)(Vts + (nd * 16 + l15) * 136 + ks2 * 32 + quad * 8);
#pragma unroll
                for (int mi = 0; mi < 2; ++mi)
                    Oacc[mi][nd] = __builtin_amdgcn_mfma_f32_16x16x32_bf16(a[mi], bb, Oacc[mi][nd], 0, 0, 0);
            }
        }
        __syncthreads();  // Ps/Vts reads done before next stage
    }

    // epilogue: O /= l, store bf16
#pragma unroll
    for (int mi = 0; mi < 2; ++mi) {
#pragma unroll
        for (int rr = 0; rr < 4; ++rr) {
            float inv = 1.f / l_run[mi][rr];
            int   q   = q0 + wave * 32 + mi * 16 + quad * 4 + rr;
#pragma unroll
            for (int nd = 0; nd < 4; ++nd)
                O[((size_t)(b * 1024 + q)) * 1024 + h * 64 + nd * 16 + l15] =
                    f2bf(Oacc[mi][nd][rr] * inv);
        }
    }
}

// ---------------------------------------------------------------------------
extern "C" void kernel_launch(void* const* d_in, const int* in_sizes, int n_in,
                              void* d_out, int out_size, void* d_ws, size_t ws_size,
                              hipStream_t stream) {
    const float* latent = (const float*)d_in[0];
    const float* data   = (const float*)d_in[1];
    const float* wq     = (const float*)d_in[2];
    const float* bq     = (const float*)d_in[3];
    const float* wk     = (const float*)d_in[4];
    const float* bk     = (const float*)d_in[5];
    const float* wv     = (const float*)d_in[6];
    const float* bv     = (const float*)d_in[7];
    const float* wo     = (const float*)d_in[8];
    const float* bo     = (const float*)d_in[9];
    float* out = (float*)d_out;

    ushort* ws   = (ushort*)d_ws;
    ushort* wqT  = ws;
    ushort* wkT  = wqT + (1u << 20);
    ushort* wvT  = wkT + (1u << 20);
    ushort* woT  = wvT + (1u << 20);
    ushort* latB = woT + (1u << 20);
    ushort* datB = latB + (8u << 20);
    ushort* Qb   = datB + (16u << 20);
    ushort* Kb   = Qb + (8u << 20);
    ushort* Vtb  = Kb + (16u << 20);
    ushort* AO   = Vtb + (16u << 20);   // needs ws_size >= 152 MB

    // f32 -> bf16 conversions
    cvt_bf16<<<(8u << 20) / (256 * 8), 256, 0, stream>>>(latent, latB, 8u << 20);
    cvt_bf16<<<(16u << 20) / (256 * 8), 256, 0, stream>>>(data, datB, 16u << 20);
    transpose_w<<<dim3(32, 32, 4), dim3(32, 8), 0, stream>>>(wq, wk, wv, wo, wqT, wkT, wvT, woT);

    // Q = latent @ wq + bq                           [8192 x 1024] bf16
    gemm_bt<0><<<dim3(8, 64), 256, 0, stream>>>(latB, wqT, bq, Qb, 1024);
    // K = data @ wk + bk                             [16384 x 1024] bf16
    gemm_bt<0><<<dim3(8, 128), 256, 0, stream>>>(datB, wkT, bk, Kb, 1024);
    // V = data @ wv + bv, stored transposed per-head [b,h,d,kv] bf16
    gemm_bt<1><<<dim3(8, 128), 256, 0, stream>>>(datB, wvT, bv, Vtb, 1024);
    // fused attention -> AO [8192 x 1024] bf16
    attn_fused<<<dim3(1024), 256, 0, stream>>>(Qb, Kb, Vtb, AO);
    // out = AO @ wo + bo                             [8192 x 1024] f32
    gemm_bt<2><<<dim3(8, 64), 256, 0, stream>>>(AO, woT, bo, out, 1024);
}

// Round 3
// 459.150 us; speedup vs baseline: 1.1110x; 1.1110x over previous
//
#include <hip/hip_runtime.h>
#include <hip/hip_bf16.h>
#include <math.h>

// Problem: B=8, NQ=1024, NKV=2048, D=1024, H=16, HD=64, inner=1024.
// f32 storage in/out; bf16 MFMA compute with fp32 accumulation.
//
// ws layout (ushort elems):
//   wqT 1M | wkT 1M | wvT 1M | woT 1M | latB 8M | datB 16M | Q 8M | K 16M
//   | Vt 16M | AO 8M   = 76M elems = 152 MB

using short4v = __attribute__((ext_vector_type(4))) short;
using short8  = __attribute__((ext_vector_type(8))) short;
using f32x4   = __attribute__((ext_vector_type(4))) float;
using uint4v  = __attribute__((ext_vector_type(4))) unsigned int;

__device__ __forceinline__ ushort f2bf(float f) {
    unsigned u = __builtin_bit_cast(unsigned, f);
    u = (u + 0x7FFFu + ((u >> 16) & 1u)) >> 16;
    return (ushort)u;
}
// pack two f32 -> two bf16 (round-half-up) in one dword: lo | hi<<16
__device__ __forceinline__ unsigned pack_bf2(float lo, float hi) {
    unsigned ulo = __builtin_bit_cast(unsigned, lo) + 0x8000u;
    unsigned uhi = __builtin_bit_cast(unsigned, hi) + 0x8000u;
    return __builtin_amdgcn_perm(uhi, ulo, 0x07060302);
}

// async global->LDS, 16B/lane. LDS dest = wave-uniform base + lane*16;
// global address is per-lane (swizzle the SOURCE address, never the dest).
__device__ __forceinline__ void gld_lds16(const ushort* g, ushort* l) {
    __builtin_amdgcn_global_load_lds(
        (const __attribute__((address_space(1))) unsigned int*)(const void*)g,
        (__attribute__((address_space(3))) unsigned int*)(void*)l,
        16, 0, 0);
}

// ---------------------------------------------------------------------------
// f32 -> bf16 conversion, 8 elems/thread
// ---------------------------------------------------------------------------
__global__ void cvt_bf16(const float* __restrict__ in, ushort* __restrict__ out, int n) {
    int i = (blockIdx.x * blockDim.x + threadIdx.x) * 8;
    if (i >= n) return;
    float4 a = *(const float4*)(in + i);
    float4 b = *(const float4*)(in + i + 4);
    short8 o;
    o[0] = (short)f2bf(a.x); o[1] = (short)f2bf(a.y);
    o[2] = (short)f2bf(a.z); o[3] = (short)f2bf(a.w);
    o[4] = (short)f2bf(b.x); o[5] = (short)f2bf(b.y);
    o[6] = (short)f2bf(b.z); o[7] = (short)f2bf(b.w);
    *(short8*)(out + i) = o;
}

// ---------------------------------------------------------------------------
// Transpose + convert weights (1024x1024 f32): out_bf16[n][k] = in_f32[k][n]
// ---------------------------------------------------------------------------
__global__ void transpose_w(const float* __restrict__ w0, const float* __restrict__ w1,
                            const float* __restrict__ w2, const float* __restrict__ w3,
                            ushort* __restrict__ o0, ushort* __restrict__ o1,
                            ushort* __restrict__ o2, ushort* __restrict__ o3) {
    __shared__ ushort tile[32][33];
    int z = blockIdx.z;
    const float* in = (z == 0) ? w0 : (z == 1) ? w1 : (z == 2) ? w2 : w3;
    ushort* out     = (z == 0) ? o0 : (z == 1) ? o1 : (z == 2) ? o2 : o3;
    int tx = threadIdx.x, ty = threadIdx.y;
    int x = blockIdx.x * 32 + tx;
    int y = blockIdx.y * 32;
#pragma unroll
    for (int i = 0; i < 32; i += 8)
        tile[ty + i][tx] = f2bf(in[(size_t)(y + ty + i) * 1024 + x]);
    __syncthreads();
    int x2 = blockIdx.y * 32 + tx;
    int y2 = blockIdx.x * 32;
#pragma unroll
    for (int i = 0; i < 32; i += 8)
        out[(size_t)(y2 + ty + i) * 1024 + x2] = tile[tx][ty + i];
}

// ---------------------------------------------------------------------------
// GEMM: C[m][n] = (sum_k A[m][k]*Bt[n][k] + bias[n]) * scale    (N=K=1024)
// MODE 0: C bf16 row-major [M][1024]
// MODE 1: V projection -> Vt bf16 [(b*1024+n)][2048], kv columns permuted by
//         pi: pos%32 = ((kv>>2)&3)*8 + ((kv>>4)&1)*4 + (kv&3)  (PV-frag-ready)
// MODE 2: C f32 row-major [M][1024]
// ---------------------------------------------------------------------------
template <int MODE>
__global__ void gemm_bt(const ushort* __restrict__ A, const ushort* __restrict__ Bt,
                        const float* __restrict__ bias, void* __restrict__ Cv,
                        int K, float scale) {
    __shared__ __align__(16) ushort As[128 * 32];
    __shared__ __align__(16) ushort Bs[128 * 32];
    const int tid  = threadIdx.x;
    const int wave = tid >> 6, lane = tid & 63;
    const int l15 = lane & 15, quad = lane >> 4;
    const int wm = wave & 1, wn = wave >> 1;
    const int m0 = blockIdx.y * 128;
    const int n0 = blockIdx.x * 128;

    f32x4 acc[4][4] = {};

    for (int k0 = 0; k0 < K; k0 += 32) {
        __syncthreads();
#pragma unroll
        for (int i = 0; i < 2; ++i) {
            int f   = (i * 256 + tid) * 8;
            int row = f >> 5, col = f & 31;
            gld_lds16(A  + (size_t)(m0 + row) * K + k0 + col, As + (i * 256 + wave * 64) * 8);
            gld_lds16(Bt + (size_t)(n0 + row) * K + k0 + col, Bs + (i * 256 + wave * 64) * 8);
        }
        __syncthreads();

        short8 a[4], b[4];
#pragma unroll
        for (int mi = 0; mi < 4; ++mi)
            a[mi] = *(const short8*)(As + (wm * 64 + mi * 16 + l15) * 32 + quad * 8);
#pragma unroll
        for (int ni = 0; ni < 4; ++ni)
            b[ni] = *(const short8*)(Bs + (wn * 64 + ni * 16 + l15) * 32 + quad * 8);
#pragma unroll
        for (int mi = 0; mi < 4; ++mi)
#pragma unroll
            for (int ni = 0; ni < 4; ++ni)
                acc[mi][ni] = __builtin_amdgcn_mfma_f32_16x16x32_bf16(a[mi], b[ni], acc[mi][ni], 0, 0, 0);
    }

    float bv[4];
    int   cols[4];
#pragma unroll
    for (int ni = 0; ni < 4; ++ni) {
        cols[ni] = n0 + wn * 64 + ni * 16 + l15;
        bv[ni]   = bias[cols[ni]];
    }
#pragma unroll
    for (int mi = 0; mi < 4; ++mi) {
        int rbase = m0 + wm * 64 + mi * 16 + quad * 4;
#pragma unroll
        for (int ni = 0; ni < 4; ++ni) {
            float v[4];
#pragma unroll
            for (int rr = 0; rr < 4; ++rr)
                v[rr] = (acc[mi][ni][rr] + bv[ni]) * scale;
            if (MODE == 1) {
                // 4 consecutive kv -> one 8B store at pi-permuted position
                int kvl = rbase & 2047;
                int pos = (kvl & ~31) + ((kvl >> 2) & 3) * 8 + ((kvl >> 4) & 1) * 4;
                size_t base = ((size_t)((rbase >> 11) * 1024 + cols[ni])) * 2048 + pos;
                uint2 o;
                o.x = pack_bf2(v[0], v[1]);
                o.y = pack_bf2(v[2], v[3]);
                *(uint2*)((ushort*)Cv + base) = o;
            } else {
#pragma unroll
                for (int rr = 0; rr < 4; ++rr) {
                    int row = rbase + rr;
                    if (MODE == 0)
                        ((ushort*)Cv)[(size_t)row * 1024 + cols[ni]] = f2bf(v[rr]);
                    else
                        ((float*)Cv)[(size_t)row * 1024 + cols[ni]] = v[rr];
                }
            }
        }
    }
}

// ---------------------------------------------------------------------------
// Fused flash attention, S^T formulation (no P round-trip through LDS).
// S^T = K·Q^T  (C-layout of S^T == B-fragment layout for PV)
// O^T = V^T · P^T, P^T taken directly from softmaxed registers.
// LDS: Qs[128][64], Ks[128][64], Vts[64][128] — unpadded, XOR-swizzled 16B
// chunks, staged with global_load_lds (source-address swizzle).
// Q pre-scaled by 0.125*log2e in projection; softmax in base-2.
// ---------------------------------------------------------------------------
__global__ __launch_bounds__(256, 3) void attn_fused(const ushort* __restrict__ Q,
                                                     const ushort* __restrict__ K,
                                                     const ushort* __restrict__ Vt,
                                                     ushort* __restrict__ O) {
    __shared__ __align__(16) ushort smem[3 * 8192];
    ushort* Qs  = smem;
    ushort* Ks  = smem + 8192;
    ushort* Vts = smem + 16384;

    const int tid  = threadIdx.x;
    const int wave = tid >> 6, lane = tid & 63;
    const int l15 = lane & 15, quad = lane >> 4;
    const int bx = blockIdx.x;
    const int qt_blk = bx & 7, h = (bx >> 3) & 15, b = bx >> 7;
    const int q0 = qt_blk * 128;

    const ushort* Qg = Q + ((size_t)(b * 1024 + q0)) * 1024 + h * 64;
    const ushort* Kg = K + ((size_t)(b * 2048)) * 1024 + h * 64;
    const ushort* Vg = Vt + ((size_t)(b * 1024 + h * 64)) * 2048;

    // --- stage Q tile [128 q][64 d], rows 128B = 8 chunks, swizzle c^(row&7)
    const int rig = lane >> 3;        // row in 8-row group
    const int cb8 = lane & 7;
    const int scb8 = cb8 ^ rig;       // (row&7)==rig inside the group
#pragma unroll
    for (int g = 0; g < 4; ++g) {
        int G = wave * 4 + g;
        gld_lds16(Qg + (size_t)(G * 8 + rig) * 1024 + scb8 * 8, Qs + G * 512);
    }

    f32x4 Oacc[4][2] = {};
    float m_run[2] = {-INFINITY, -INFINITY};
    float l_run[2] = {0.f, 0.f};

    const int riv = lane >> 4;        // row in 4-row group (V)
    const int cb16 = lane & 15;

    for (int kv0 = 0; kv0 < 2048; kv0 += 128) {
        __syncthreads();   // previous iter's LDS reads complete
        // --- stage K [128 kv][64 d] and V^T [64 d][128 kv(pi-permuted)]
#pragma unroll
        for (int g = 0; g < 4; ++g) {
            int G = wave * 4 + g;
            gld_lds16(Kg + (size_t)(kv0 + G * 8 + rig) * 1024 + scb8 * 8, Ks + G * 512);
            int vrow = G * 4 + riv;
            int scv = cb16 ^ (vrow & 15);
            gld_lds16(Vg + (size_t)vrow * 2048 + kv0 + scv * 8, Vts + G * 512);
        }
        __syncthreads();   // drains vmcnt -> all staged data visible

        // --- S^T = K · Q^T : tiles [kvt 0..7][qt 0..1], wave owns 32 q cols
        f32x4 s[8][2] = {};
#pragma unroll
        for (int ks = 0; ks < 2; ++ks) {
            int ck = ((ks * 4 + quad) ^ (l15 & 7)) * 8;   // swizzled chunk col
            short8 bq[2];
#pragma unroll
            for (int qt = 0; qt < 2; ++qt) {
                int row = wave * 32 + qt * 16 + l15;
                bq[qt] = *(const short8*)(Qs + row * 64 + ck);
            }
#pragma unroll
            for (int kvt = 0; kvt < 8; ++kvt) {
                short8 ak = *(const short8*)(Ks + (kvt * 16 + l15) * 64 + ck);
#pragma unroll
                for (int qt = 0; qt < 2; ++qt)
                    s[kvt][qt] = __builtin_amdgcn_mfma_f32_16x16x32_bf16(ak, bq[qt], s[kvt][qt], 0, 0, 0);
            }
        }

        // --- online softmax over kv (rows); per-lane: 32 vals per q-column
        unsigned pk[8][2][2];
#pragma unroll
        for (int qt = 0; qt < 2; ++qt) {
            float mx = -INFINITY;
#pragma unroll
            for (int kvt = 0; kvt < 8; ++kvt)
#pragma unroll
                for (int rr = 0; rr < 4; ++rr) mx = fmaxf(mx, s[kvt][qt][rr]);
            mx = fmaxf(mx, __shfl_xor(mx, 16));
            mx = fmaxf(mx, __shfl_xor(mx, 32));
            float mnew = fmaxf(m_run[qt], mx);
            float al   = exp2f(m_run[qt] - mnew);
            float sum  = 0.f;
#pragma unroll
            for (int kvt = 0; kvt < 8; ++kvt)
#pragma unroll
                for (int rr = 0; rr < 4; ++rr) {
                    float p = exp2f(s[kvt][qt][rr] - mnew);
                    s[kvt][qt][rr] = p;
                    sum += p;
                }
            sum += __shfl_xor(sum, 16);
            sum += __shfl_xor(sum, 32);
            m_run[qt] = mnew;
            l_run[qt] = l_run[qt] * al + sum;
#pragma unroll
            for (int kvt = 0; kvt < 8; ++kvt) {
                pk[kvt][qt][0] = pack_bf2(s[kvt][qt][0], s[kvt][qt][1]);
                pk[kvt][qt][1] = pack_bf2(s[kvt][qt][2], s[kvt][qt][3]);
            }
#pragma unroll
            for (int dt = 0; dt < 4; ++dt)
#pragma unroll
                for (int rr = 0; rr < 4; ++rr) Oacc[dt][qt][rr] *= al;
        }

        // --- O^T += V^T · P^T : P^T B-frags come straight from pk registers.
        // k-pair sp covers kv tiles {2sp, 2sp+1}; V^T pi-layout makes the
        // matching A-frag one contiguous b128.
#pragma unroll
        for (int sp = 0; sp < 4; ++sp) {
#pragma unroll
            for (int dt = 0; dt < 4; ++dt) {
                int row = dt * 16 + l15;
                int cv = ((sp * 4 + quad) ^ l15) * 8;
                short8 av = *(const short8*)(Vts + row * 128 + cv);
#pragma unroll
                for (int qt = 0; qt < 2; ++qt) {
                    uint4v u = {pk[2 * sp][qt][0], pk[2 * sp][qt][1],
                                pk[2 * sp + 1][qt][0], pk[2 * sp + 1][qt][1]};
                    short8 bp = __builtin_bit_cast(short8, u);
                    Oacc[dt][qt] = __builtin_amdgcn_mfma_f32_16x16x32_bf16(av, bp, Oacc[dt][qt], 0, 0, 0);
                }
            }
        }
    }

    // --- epilogue: O = (O^T)^T / l, packed 8B stores (4 d-contiguous bf16)
#pragma unroll
    for (int qt = 0; qt < 2; ++qt) {
        float inv = 1.f / l_run[qt];
        int qg = q0 + wave * 32 + qt * 16 + l15;
#pragma unroll
        for (int dt = 0; dt < 4; ++dt) {
            uint2 o;
            o.x = pack_bf2(Oacc[dt][qt][0] * inv, Oacc[dt][qt][1] * inv);
            o.y = pack_bf2(Oacc[dt][qt][2] * inv, Oacc[dt][qt][3] * inv);
            *(uint2*)(O + ((size_t)(b * 1024 + qg)) * 1024 + h * 64 + dt * 16 + quad * 4) = o;
        }
    }
}

// ---------------------------------------------------------------------------
extern "C" void kernel_launch(void* const* d_in, const int* in_sizes, int n_in,
                              void* d_out, int out_size, void* d_ws, size_t ws_size,
                              hipStream_t stream) {
    const float* latent = (const float*)d_in[0];
    const float* data   = (const float*)d_in[1];
    const float* wq     = (const float*)d_in[2];
    const float* bq     = (const float*)d_in[3];
    const float* wk     = (const float*)d_in[4];
    const float* bk     = (const float*)d_in[5];
    const float* wv     = (const float*)d_in[6];
    const float* bv     = (const float*)d_in[7];
    const float* wo     = (const float*)d_in[8];
    const float* bo     = (const float*)d_in[9];
    float* out = (float*)d_out;

    ushort* ws   = (ushort*)d_ws;
    ushort* wqT  = ws;
    ushort* wkT  = wqT + (1u << 20);
    ushort* wvT  = wkT + (1u << 20);
    ushort* woT  = wvT + (1u << 20);
    ushort* latB = woT + (1u << 20);
    ushort* datB = latB + (8u << 20);
    ushort* Qb   = datB + (16u << 20);
    ushort* Kb   = Qb + (8u << 20);
    ushort* Vtb  = Kb + (16u << 20);
    ushort* AO   = Vtb + (16u << 20);   // needs ws_size >= 152 MB

    cvt_bf16<<<(8u << 20) / (256 * 8), 256, 0, stream>>>(latent, latB, 8u << 20);
    cvt_bf16<<<(16u << 20) / (256 * 8), 256, 0, stream>>>(data, datB, 16u << 20);
    transpose_w<<<dim3(32, 32, 4), dim3(32, 8), 0, stream>>>(wq, wk, wv, wo, wqT, wkT, wvT, woT);

    const float qscale = 0.125f * 1.44269504088896340736f;  // HD^-0.5 * log2(e)
    // Q = (latent @ wq + bq) * qscale                [8192 x 1024] bf16
    gemm_bt<0><<<dim3(8, 64), 256, 0, stream>>>(latB, wqT, bq, Qb, 1024, qscale);
    // K = data @ wk + bk                             [16384 x 1024] bf16
    gemm_bt<0><<<dim3(8, 128), 256, 0, stream>>>(datB, wkT, bk, Kb, 1024, 1.0f);
    // V^T per-head, pi-permuted kv                   [8192 x 2048] bf16
    gemm_bt<1><<<dim3(8, 128), 256, 0, stream>>>(datB, wvT, bv, Vtb, 1024, 1.0f);
    // fused attention -> AO [8192 x 1024] bf16
    attn_fused<<<dim3(1024), 256, 0, stream>>>(Qb, Kb, Vtb, AO);
    // out = AO @ wo + bo                             [8192 x 1024] f32
    gemm_bt<2><<<dim3(8, 64), 256, 0, stream>>>(AO, woT, bo, out, 1024, 1.0f);
}